// Round 3
// baseline (411.981 us; speedup 1.0000x reference)
//
#include <hip/hip_runtime.h>

typedef unsigned short u16;
typedef __attribute__((ext_vector_type(8))) __bf16 bf16x8;
typedef __attribute__((ext_vector_type(4))) float f32x4;
typedef __attribute__((ext_vector_type(8))) unsigned short us8v;

__device__ __forceinline__ u16 f2bf(float x){
  union { float f; unsigned u; } v; v.f = x;
  unsigned r = v.u + 0x7fffu + ((v.u >> 16) & 1u);
  return (u16)(r >> 16);
}
__device__ __forceinline__ float bf2f(u16 h){
  union { unsigned u; float f; } v; v.u = ((unsigned)h) << 16;
  return v.f;
}
// async global->LDS, 16B per lane. lds ptr must be wave-uniform; HW writes base + lane*16.
__device__ __forceinline__ void gld16(const void* g, void* l){
  __builtin_amdgcn_global_load_lds((const __attribute__((address_space(1))) unsigned int*)g,
                                   (__attribute__((address_space(3))) unsigned int*)l, 16, 0, 0);
}

// ---------- weight transposes + ln1 in ONE kernel ----------
// blocks 0..4095: Wq/Wk/Wv/Wo; 4096..12287: Wup (G/U interleave); 12288..16383: Wdown;
// blocks 16384..20479: ln1 rows (Hc = LN(Q_in)*g1+b1 + X)
__global__ __launch_bounds__(256) void tr_all(
    const float* __restrict__ Wq, const float* __restrict__ Wk,
    const float* __restrict__ Wv, const float* __restrict__ Wo,
    const float* __restrict__ Wup, const float* __restrict__ Wdown,
    u16* __restrict__ WqkvT, u16* __restrict__ WoT,
    u16* __restrict__ WupT, u16* __restrict__ WdT,
    const float* __restrict__ Qin, const float* __restrict__ X,
    const float* __restrict__ g1, const float* __restrict__ b1,
    u16* __restrict__ HcB)
{
  __shared__ float t[32][33];
  int tx = threadIdx.x, ty = threadIdx.y;
  int id = blockIdx.x;
  if (id >= 16384){
    int row = id - 16384, tid = ty*32 + tx;
    const float4 x = ((const float4*)(Qin + (size_t)row*1024))[tid];
    float s = x.x + x.y + x.z + x.w;
    float sq = x.x*x.x + x.y*x.y + x.z*x.z + x.w*x.w;
    #pragma unroll
    for (int o=32;o>0;o>>=1){ s += __shfl_xor(s, o); sq += __shfl_xor(sq, o); }
    __shared__ float ss[4], ssq[4];
    int wid = tid>>6;
    if ((tid&63)==0){ ss[wid]=s; ssq[wid]=sq; }
    __syncthreads();
    s = ss[0]+ss[1]+ss[2]+ss[3]; sq = ssq[0]+ssq[1]+ssq[2]+ssq[3];
    float mu = s*(1.0f/1024.0f);
    float var = sq*(1.0f/1024.0f) - mu*mu;
    float rstd = rsqrtf(var + 1e-5f);
    float4 xx = ((const float4*)(X + (size_t)row*1024))[tid];
    float4 gv = ((const float4*)g1)[tid];
    float4 bv = ((const float4*)b1)[tid];
    ushort4 o;
    o.x = f2bf((x.x-mu)*rstd*gv.x + bv.x + xx.x);
    o.y = f2bf((x.y-mu)*rstd*gv.y + bv.y + xx.y);
    o.z = f2bf((x.z-mu)*rstd*gv.z + bv.z + xx.z);
    o.w = f2bf((x.w-mu)*rstd*gv.w + bv.w + xx.w);
    ((ushort4*)(HcB + (size_t)row*1024))[tid] = o;
    return;
  }
  if (id < 4096){
    int w = id >> 10, b = id & 1023;
    int c0 = (b & 31)*32, r0 = (b >> 5)*32;
    const float* S = (w==0)?Wq:(w==1)?Wk:(w==2)?Wv:Wo;
    u16* D = (w==3)? WoT : (WqkvT + (size_t)w*1024*1024);
    #pragma unroll
    for (int j=0;j<32;j+=8) t[ty+j][tx] = S[(size_t)(r0+ty+j)*1024 + (c0+tx)];
    __syncthreads();
    #pragma unroll
    for (int j=0;j<32;j+=8) D[(size_t)(c0+ty+j)*1024 + (r0+tx)] = f2bf(t[tx][ty+j]);
  } else if (id < 12288){
    int b = id - 4096;
    int c0 = (b & 255)*32, r0 = (b >> 8)*32;
    #pragma unroll
    for (int j=0;j<32;j+=8) t[ty+j][tx] = Wup[(size_t)(r0+ty+j)*8192 + (c0+tx)];
    __syncthreads();
    #pragma unroll
    for (int j=0;j<32;j+=8){
      int c = c0 + ty + j;
      int rdst = (c < 4096) ? ((c>>4)*32 + (c&15)) : (((c-4096)>>4)*32 + 16 + (c&15));
      WupT[(size_t)rdst*1024 + (r0+tx)] = f2bf(t[tx][ty+j]);
    }
  } else {
    int b = id - 12288;
    int c0 = (b & 31)*32, r0 = (b >> 5)*32;
    #pragma unroll
    for (int j=0;j<32;j+=8) t[ty+j][tx] = Wdown[(size_t)(r0+ty+j)*1024 + (c0+tx)];
    __syncthreads();
    #pragma unroll
    for (int j=0;j<32;j+=8) WdT[(size_t)(c0+ty+j)*4096 + (r0+tx)] = f2bf(t[tx][ty+j]);
  }
}

// ---------- ln2: Qint = Q_in + softplus(dt)*(P0+P1); Qn2 = LN(Qint)*g+b (bf16 partials) ----------
__global__ __launch_bounds__(256) void ln2_kernel(const u16* __restrict__ P,
    const float* __restrict__ Qin, const float* __restrict__ dtp,
    const float* __restrict__ g, const float* __restrict__ b,
    float* __restrict__ Qint, u16* __restrict__ Qn2){
  int row = blockIdx.x, tid = threadIdx.x;
  float sp = log1pf(__expf(dtp[0]));
  size_t off = (size_t)row*1024;
  ushort4 p0 = ((const ushort4*)(P + off))[tid];
  ushort4 p1 = ((const ushort4*)(P + 4194304 + off))[tid];
  float4 q  = ((const float4*)(Qin + off))[tid];
  float4 x;
  x.x = q.x + sp*(bf2f(p0.x)+bf2f(p1.x)); x.y = q.y + sp*(bf2f(p0.y)+bf2f(p1.y));
  x.z = q.z + sp*(bf2f(p0.z)+bf2f(p1.z)); x.w = q.w + sp*(bf2f(p0.w)+bf2f(p1.w));
  ((float4*)(Qint + off))[tid] = x;
  float s = x.x + x.y + x.z + x.w;
  float sq = x.x*x.x + x.y*x.y + x.z*x.z + x.w*x.w;
  #pragma unroll
  for (int o=32;o>0;o>>=1){ s += __shfl_xor(s, o); sq += __shfl_xor(sq, o); }
  __shared__ float ss[4], ssq[4];
  int wid = tid>>6;
  if ((tid&63)==0){ ss[wid]=s; ssq[wid]=sq; }
  __syncthreads();
  s = ss[0]+ss[1]+ss[2]+ss[3]; sq = ssq[0]+ssq[1]+ssq[2]+ssq[3];
  float mu = s*(1.0f/1024.0f);
  float var = sq*(1.0f/1024.0f) - mu*mu;
  float rstd = rsqrtf(var + 1e-5f);
  float4 gv = ((const float4*)g)[tid];
  float4 bv = ((const float4*)b)[tid];
  ushort4 o;
  o.x = f2bf((x.x-mu)*rstd*gv.x + bv.x);
  o.y = f2bf((x.y-mu)*rstd*gv.y + bv.y);
  o.z = f2bf((x.z-mu)*rstd*gv.z + bv.z);
  o.w = f2bf((x.w-mu)*rstd*gv.w + bv.w);
  ((ushort4*)(Qn2 + off))[tid] = o;
}

// ---------- fused QKV GEMM (BK=64), A[4096][1024] @ WqkvT[3072][1024]^T ----------
__global__ __launch_bounds__(256, 3) void gemm_qkv(
    const u16* __restrict__ A, const u16* __restrict__ Bt, void* __restrict__ Op)
{
  __shared__ u16 As[128*64];
  __shared__ u16 Bs[128*64];
  const int tid = threadIdx.x, wid = tid>>6, lane = tid&63;
  const int g = lane>>4, l = lane&15, l7 = l&7;
  const int row0 = blockIdx.x*128, col0 = blockIdx.y*128;
  const int wr = (wid&1)*64, wc = (wid>>1)*64;
  f32x4 acc[4][4] = {};
  for (int k0 = 0; k0 < 1024; k0 += 64){
    __syncthreads();
    #pragma unroll
    for (int i=0;i<4;i++){
      int ch0 = i*256 + wid*64;
      int ch = ch0 + lane;
      int r = ch >> 3, c = ch & 7;
      int cs = c ^ (r & 7);     // 8-phase XOR source swizzle -> conflict-free frag reads
      gld16(A  + (size_t)(row0+r)*1024 + k0 + cs*8, (char*)As + ch0*16);
      gld16(Bt + (size_t)(col0+r)*1024 + k0 + cs*8, (char*)Bs + ch0*16);
    }
    __syncthreads();
    #pragma unroll
    for (int kk=0; kk<2; kk++){
      bf16x8 a[4], b[4];
      #pragma unroll
      for (int i=0;i<4;i++) a[i] = *(const bf16x8*)(As + (wr + i*16 + l)*64 + (((kk*4+g)^l7)*8));
      #pragma unroll
      for (int j=0;j<4;j++) b[j] = *(const bf16x8*)(Bs + (wc + j*16 + l)*64 + (((kk*4+g)^l7)*8));
      #pragma unroll
      for (int i=0;i<4;i++)
        #pragma unroll
        for (int j=0;j<4;j++)
          acc[i][j] = __builtin_amdgcn_mfma_f32_16x16x32_bf16(a[i], b[j], acc[i][j], 0, 0, 0);
    }
  }
  u16* P = (u16*)Op;
  #pragma unroll
  for (int i=0;i<4;i++)
   #pragma unroll
   for (int j=0;j<4;j++){
     int col = col0 + wc + j*16 + l;
     int qk = col >> 10, c = col & 1023;
     int h = c >> 6, d = c & 63;
     int rowb = row0 + wr + i*16 + g*4;
     int bb = rowb >> 11, n = rowb & 2047;
     if (qk == 2){
       ushort4 vs;
       vs.x = f2bf(acc[i][j][0]); vs.y = f2bf(acc[i][j][1]);
       vs.z = f2bf(acc[i][j][2]); vs.w = f2bf(acc[i][j][3]);
       *(ushort4*)(P + (size_t)8388608 + (((size_t)(bb*16 + h))*64 + d)*2048 + n) = vs;
     } else {
       #pragma unroll
       for (int r=0;r<4;r++){
         float v = acc[i][j][r];
         float phi = v > 0.f ? v + 1.f : __expf(v);
         P[(size_t)qk*4194304 + (((size_t)(bb*16 + h))*2048 + (n+r))*64 + d] = f2bf(phi);
       }
     }
   }
}

// ---------- Wup GEMM: 256x256 tile, BK=64, 512 thr, fine-grained 4-phase/K-tile schedule.
// Block C = 4 quadrants of 128x128; phase q computes one quadrant (16 MFMA/wave).
// Operand reg-caching => LDS reads/phase = 12/8/4/0; one 128x64 half-tile staged per phase.
// RACE-SAFE WAIT PLACEMENT (fix of r2): counted vmcnt sits BEFORE a barrier; reads of a slot
// happen only in a phase AFTER the phase whose wait+barrier certified it (wait->barrier->read).
// Per-phase order: [reads certified last phase] [stage] [vmcnt(N)] BAR [lgkmcnt(0)] MFMA BAR.
// FIFO (2 loads/STG/wave), steady state entering t.P0: 10 = [A(t)h1,B(t)h1,A(t+1)h0,B(t+1)h0,A(t+1)h1]
//   P0: reads a0=A(t)h0,b0=B(t)h0; +B(t+1)h1=12; vmcnt(10) retires A(t)h1  -> BAR; MFMA(0,0)
//   P1: reads a1=A(t)h1;           +A(t+2)h0=12; vmcnt(10) retires B(t)h1  -> BAR; MFMA(1,0)
//   P2: reads b1=B(t)h1;           +B(t+2)h0=12; (no wait)                 -> BAR; MFMA(1,1)
//   P3: (no reads)                 +A(t+2)h1=14; vmcnt(10) retires A/B(t+1)h0 -> BAR; MFMA(0,1)
// Slot overwrites are >=1 barrier after last read of old contents. Tail re-stages same bytes.
// Prologue ends with vmcnt(10)+barrier so t=0.P0 reads are certified.
__global__ __launch_bounds__(512, 2) void gemm_wide_up(
    const u16* __restrict__ A, const u16* __restrict__ Bt, u16* __restrict__ Op)
{
  __shared__ __attribute__((aligned(16))) u16 As[2][256*64];   // 2 x 32KB
  __shared__ __attribute__((aligned(16))) u16 Bs[2][256*64];   // 2 x 32KB -> 128KB, 1 block/CU
  const int tid = threadIdx.x, wid = tid>>6, lane = tid&63;
  const int g = lane>>4, l = lane&15, l7 = l&7;
  const int wm = wid>>2, wn = wid&3;
  const int bid = blockIdx.x;
  const int lid = (bid & 7)*64 + (bid >> 3);    // XCD-contiguous remap (512 = 8*64, bijective)
  const int bx = lid & 15, by = lid >> 4;
  const int row0 = bx*256, col0 = by*256;
  // staging: 1024 16B-chunks per half-tile; thread covers chunk tid (rows 0..63) and 512+tid
  // (rows 64..127) of the half. XOR source swizzle: LDS[r][c] = global[r][c^(r&7)].
  const int rA = tid >> 3;
  const int cs = (tid & 7) ^ (rA & 7);
  const u16* A0p = A  + (size_t)(row0 + rA)*1024 + cs*8;
  const u16* A1p = A  + (size_t)(row0 + 64 + rA)*1024 + cs*8;
  const u16* B0p = Bt + (size_t)(col0 + rA)*1024 + cs*8;
  const u16* B1p = Bt + (size_t)(col0 + 64 + rA)*1024 + cs*8;
  const int d0 = (wid*64)*16;          // LDS byte offset, chunks 0..511 region (wave-uniform)
  const int d1 = (512 + wid*64)*16;    // chunks 512..1023
  // fragment read constants
  const int kc0 = (g ^ l7)*8, kc1 = ((4+g) ^ l7)*8;
  const int awo = (wm*64 + l)*64;
  const int bwo = (wn*32 + l)*64;

#define STG_A(buf, half, T) do{ \
  gld16(A0p + (size_t)(half)*131072 + (size_t)(T)*64, (char*)&As[buf][0] + (half)*16384 + d0); \
  gld16(A1p + (size_t)(half)*131072 + (size_t)(T)*64, (char*)&As[buf][0] + (half)*16384 + d1); }while(0)
#define STG_B(buf, half, T) do{ \
  gld16(B0p + (size_t)(half)*131072 + (size_t)(T)*64, (char*)&Bs[buf][0] + (half)*16384 + d0); \
  gld16(B1p + (size_t)(half)*131072 + (size_t)(T)*64, (char*)&Bs[buf][0] + (half)*16384 + d1); }while(0)
#define VMW do{ asm volatile("s_waitcnt vmcnt(10)" ::: "memory"); __builtin_amdgcn_sched_barrier(0); }while(0)
#define BAR do{ __builtin_amdgcn_sched_barrier(0); __builtin_amdgcn_s_barrier(); __builtin_amdgcn_sched_barrier(0); }while(0)
#define LGW do{ asm volatile("s_waitcnt lgkmcnt(0)" ::: "memory"); __builtin_amdgcn_sched_barrier(0); }while(0)
#define MFMA_Q(QM,QN,AV,BV) do{ \
  __builtin_amdgcn_s_setprio(1); \
  _Pragma("unroll") \
  for (int kk=0;kk<2;kk++) \
    _Pragma("unroll") \
    for (int i=0;i<4;i++) \
      _Pragma("unroll") \
      for (int j=0;j<2;j++) \
        acc[QM][QN][i][j] = __builtin_amdgcn_mfma_f32_16x16x32_bf16(AV[i][kk], BV[j][kk], acc[QM][QN][i][j], 0,0,0); \
  __builtin_amdgcn_s_setprio(0); }while(0)

  f32x4 acc[2][2][4][2] = {};
  bf16x8 a0[4][2], a1[4][2], b0[2][2], b1[2][2];

  // prologue (oldest->newest): A0(0),B0(0),A1(0),B1(0),A0(1),B0(1),A1(1) = 14 loads
  STG_A(0, 0, 0);
  STG_B(0, 0, 0);
  STG_A(0, 1, 0);
  STG_B(0, 1, 0);
  STG_A(1, 0, 1);
  STG_B(1, 0, 1);
  STG_A(1, 1, 1);
  // certify A(0)h0 + B(0)h0 for t=0.P0 reads: wait -> barrier -> read
  VMW;
  BAR;

  #pragma unroll 2
  for (int t = 0; t < 16; ++t){
    const int c = t & 1;
    const u16* Ac = &As[c][0];
    const u16* Bc = &Bs[c][0];
    const int T1 = (t < 15) ? t+1 : 14;   // B-h1 stage target (clamped: same slot, same bytes)
    const int T2 = (t < 14) ? t+2 : t;    // A-h0/B-h0/A-h1 stage target
    // ---- P0: quadrant (0,0) ----
    #pragma unroll
    for (int i=0;i<4;i++){
      a0[i][0] = *(const bf16x8*)(Ac + awo + i*1024 + kc0);
      a0[i][1] = *(const bf16x8*)(Ac + awo + i*1024 + kc1);
    }
    #pragma unroll
    for (int j=0;j<2;j++){
      b0[j][0] = *(const bf16x8*)(Bc + bwo + j*1024 + kc0);
      b0[j][1] = *(const bf16x8*)(Bc + bwo + j*1024 + kc1);
    }
    STG_B(c^1, 1, T1);
    VMW;                 // retires A(t)h1 -> certified for P1 after BAR
    BAR; LGW;
    MFMA_Q(0,0,a0,b0);
    BAR;
    // ---- P1: quadrant (1,0) ----
    #pragma unroll
    for (int i=0;i<4;i++){
      a1[i][0] = *(const bf16x8*)(Ac + 8192 + awo + i*1024 + kc0);
      a1[i][1] = *(const bf16x8*)(Ac + 8192 + awo + i*1024 + kc1);
    }
    STG_A(c, 0, T2);
    VMW;                 // retires B(t)h1 -> certified for P2 after BAR
    BAR; LGW;
    MFMA_Q(1,0,a1,b0);
    BAR;
    // ---- P2: quadrant (1,1) ----
    #pragma unroll
    for (int j=0;j<2;j++){
      b1[j][0] = *(const bf16x8*)(Bc + 8192 + bwo + j*1024 + kc0);
      b1[j][1] = *(const bf16x8*)(Bc + 8192 + bwo + j*1024 + kc1);
    }
    STG_B(c, 0, T2);
    // no wait: P3 has no LDS reads
    BAR; LGW;
    MFMA_Q(1,1,a1,b1);
    BAR;
    // ---- P3: quadrant (0,1), no LDS reads (a0,b1 reg-cached) ----
    STG_A(c, 1, T2);
    VMW;                 // retires A(t+1)h0 + B(t+1)h0 -> certified for t+1.P0 after BAR
    BAR;
    MFMA_Q(0,1,a0,b1);
    BAR;
  }
  asm volatile("s_waitcnt vmcnt(0)" ::: "memory");
#undef STG_A
#undef STG_B
#undef VMW
#undef BAR
#undef LGW
#undef MFMA_Q

  #pragma unroll
  for (int Qm=0;Qm<2;Qm++)
   #pragma unroll
   for (int Qn=0;Qn<2;Qn++)
    #pragma unroll
    for (int i=0;i<4;i++)
     #pragma unroll
     for (int r=0;r<4;r++){
       int row = row0 + Qm*128 + wm*64 + i*16 + g*4 + r;
       int pair = (col0 + Qn*128 + wn*32) >> 5;
       float G = acc[Qm][Qn][i][0][r], U = acc[Qm][Qn][i][1][r];
       float hf = G/(1.f+__expf(-G))*U;
       Op[(size_t)row*4096 + pair*16 + l] = f2bf(hf);
     }
}

// ---------- split-K GEMM (BK=64): bf16 partial per z-slice ----------
__global__ __launch_bounds__(256, 3) void gemm_part(
    const u16* __restrict__ A, const u16* __restrict__ Bt,
    int Nc, int K, int Ks, u16* __restrict__ Op)
{
  __shared__ u16 As[128*64];
  __shared__ u16 Bs[128*64];
  const int tid = threadIdx.x, wid = tid>>6, lane = tid&63;
  const int g = lane>>4, l = lane&15, l7 = l&7;
  const int row0 = blockIdx.x*128, col0 = blockIdx.y*128;
  const int kbase = blockIdx.z*Ks;
  const int wr = (wid&1)*64, wc = (wid>>1)*64;
  f32x4 acc[4][4] = {};
  for (int k0 = kbase; k0 < kbase + Ks; k0 += 64){
    __syncthreads();
    #pragma unroll
    for (int i=0;i<4;i++){
      int ch0 = i*256 + wid*64;
      int ch = ch0 + lane;
      int r = ch >> 3, c = ch & 7;
      int cs = c ^ (r & 7);
      gld16(A  + (size_t)(row0+r)*K + k0 + cs*8, (char*)As + ch0*16);
      gld16(Bt + (size_t)(col0+r)*K + k0 + cs*8, (char*)Bs + ch0*16);
    }
    __syncthreads();
    #pragma unroll
    for (int kk=0; kk<2; kk++){
      bf16x8 a[4], b[4];
      #pragma unroll
      for (int i=0;i<4;i++) a[i] = *(const bf16x8*)(As + (wr + i*16 + l)*64 + (((kk*4+g)^l7)*8));
      #pragma unroll
      for (int j=0;j<4;j++) b[j] = *(const bf16x8*)(Bs + (wc + j*16 + l)*64 + (((kk*4+g)^l7)*8));
      #pragma unroll
      for (int i=0;i<4;i++)
        #pragma unroll
        for (int j=0;j<4;j++)
          acc[i][j] = __builtin_amdgcn_mfma_f32_16x16x32_bf16(a[i], b[j], acc[i][j], 0, 0, 0);
    }
  }
  u16* P = Op + (size_t)blockIdx.z*4194304;
  #pragma unroll
  for (int i=0;i<4;i++)
   #pragma unroll
   for (int j=0;j<4;j++)
    #pragma unroll
    for (int r=0;r<4;r++){
      int row = row0 + wr + i*16 + g*4 + r;
      int col = col0 + wc + j*16 + l;
      P[(size_t)row*Nc + col] = f2bf(acc[i][j][r]);
    }
}

// ---------- out = Qint + Pd0 + Pd1 (bf16 partials) ----------
__global__ __launch_bounds__(256) void reduce_out(const float* __restrict__ Qint,
    const u16* __restrict__ P, float* __restrict__ out){
  size_t i = (size_t)blockIdx.x*256 + threadIdx.x;
  float4 a  = ((const float4*)Qint)[i];
  ushort4 p0 = ((const ushort4*)P)[i];
  ushort4 p1 = ((const ushort4*)(P + 4194304))[i];
  float4 o;
  o.x = a.x + bf2f(p0.x) + bf2f(p1.x); o.y = a.y + bf2f(p0.y) + bf2f(p1.y);
  o.z = a.z + bf2f(p0.z) + bf2f(p1.z); o.w = a.w + bf2f(p0.w) + bf2f(p1.w);
  ((float4*)out)[i] = o;
}

// ---------- linear attention with relu^2, flash-style ----------
// Q-fragments in registers (loop-invariant). LDS = sK 16 + sV 16 + sW 32 = 64KB -> 2 blocks/CU.
__global__ __launch_bounds__(256, 2) void attn_kernel(
    const u16* __restrict__ PhiQ, const u16* __restrict__ PhiK,
    const u16* __restrict__ Vt, u16* __restrict__ Mb)
{
  __shared__ u16 sK[2][128][32];
  __shared__ u16 sV[4][64][32];
  __shared__ u16 sW[128*128];
  const int tid = threadIdx.x, wid = tid>>6, lane = tid&63;
  const int g = lane>>4, l = lane&15;
  const int l3 = l & 3;
  const int q0 = blockIdx.x*128, bh = blockIdx.y;
  const u16* Q  = PhiQ + (size_t)bh*2048*64;
  const u16* Kb = PhiK + (size_t)bh*2048*64;
  const u16* V  = Vt   + (size_t)bh*64*2048;
  bf16x8 bq[8][2];
  #pragma unroll
  for (int ct=0;ct<8;ct++)
    #pragma unroll
    for (int ks=0;ks<2;ks++)
      bq[ct][ks] = *(const bf16x8*)(Q + (size_t)(q0 + ct*16 + l)*64 + ks*32 + g*8);
  f32x4 accO[2][4] = {};
  float rsum[8] = {0.f,0.f,0.f,0.f,0.f,0.f,0.f,0.f};
  for (int m0 = 0; m0 < 2048; m0 += 128){
    __syncthreads();
    #pragma unroll
    for (int ks=0; ks<2; ks++)
      #pragma unroll
      for (int i=0;i<2;i++){
        int ch0 = i*256 + wid*64;
        int ch = ch0 + lane;
        int r = ch >> 2, q = ch & 3;
        int qs = q ^ (r & 3);
        gld16(Kb + (size_t)(m0+r)*64 + ks*32 + qs*8, (char*)&sK[ks][0][0] + ch0*16);
      }
    #pragma unroll
    for (int c=0; c<4; c++){
      int ch0 = wid*64;
      int ch = ch0 + lane;
      int d = ch >> 2, q = ch & 3;
      int qs = q ^ (d & 3);
      gld16(V + (size_t)d*2048 + m0 + c*32 + qs*8, (char*)&sV[c][0][0] + ch0*16);
    }
    __syncthreads();
    f32x4 st[2][8] = {};
    bf16x8 ak[2][2];
    #pragma unroll
    for (int rt=0;rt<2;rt++)
      #pragma unroll
      for (int ks=0;ks<2;ks++)
        ak[rt][ks] = *(const bf16x8*)&sK[ks][wid*32 + rt*16 + l][(g^l3)*8];
    #pragma unroll
    for (int ct=0;ct<8;ct++){
      #pragma unroll
      for (int ks=0;ks<2;ks++){
        st[0][ct] = __builtin_amdgcn_mfma_f32_16x16x32_bf16(ak[0][ks], bq[ct][ks], st[0][ct], 0,0,0);
        st[1][ct] = __builtin_amdgcn_mfma_f32_16x16x32_bf16(ak[1][ks], bq[ct][ks], st[1][ct], 0,0,0);
      }
    }
    #pragma unroll
    for (int ct=0;ct<8;ct++){
      float part = 0.f;
      #pragma unroll
      for (int rt=0;rt<2;rt++){
        float s0 = fmaxf(st[rt][ct][0], 0.f), s1 = fmaxf(st[rt][ct][1], 0.f);
        float s2 = fmaxf(st[rt][ct][2], 0.f), s3 = fmaxf(st[rt][ct][3], 0.f);
        float w0 = s0*s0, w1 = s1*s1, w2 = s2*s2, w3 = s3*s3;
        part += w0 + w1 + w2 + w3;
        int n = ct*16 + l;
        int mblk = wid*4 + rt*2 + (g>>1);
        ushort4 w4;
        w4.x = f2bf(w0); w4.y = f2bf(w1); w4.z = f2bf(w2); w4.w = f2bf(w3);
        *(ushort4*)(sW + n*128 + ((mblk ^ l)*8) + (g&1)*4) = w4;
      }
      rsum[ct] += part;
    }
    __syncthreads();
    #pragma unroll
    for (int ks=0;ks<4;ks++){
      int n0 = wid*32 + l, n1 = wid*32 + 16 + l;
      bf16x8 aw0 = *(const bf16x8*)(sW + n0*128 + (((ks*4+g) ^ (n0&15))*8));
      bf16x8 aw1 = *(const bf16x8*)(sW + n1*128 + (((ks*4+g) ^ (n1&15))*8));
      #pragma unroll
      for (int ct=0;ct<4;ct++){
        bf16x8 bv = *(const bf16x8*)&sV[ks][ct*16 + l][(g^l3)*8];
        accO[0][ct] = __builtin_amdgcn_mfma_f32_16x16x32_bf16(aw0, bv, accO[0][ct], 0,0,0);
        accO[1][ct] = __builtin_amdgcn_mfma_f32_16x16x32_bf16(aw1, bv, accO[1][ct], 0,0,0);
      }
    }
  }
  __syncthreads();
  float* sRS = (float*)sW;
  float* sNorm = ((float*)sW) + 512;
  #pragma unroll
  for (int ct=0;ct<8;ct++){
    float v = rsum[ct];
    v += __shfl_xor(v, 16);
    v += __shfl_xor(v, 32);
    rsum[ct] = v;
  }
  if (g == 0){
    #pragma unroll
    for (int ct=0;ct<8;ct++) sRS[wid*128 + ct*16 + l] = rsum[ct];
  }
  __syncthreads();
  if (tid < 128) sNorm[tid] = sRS[tid] + sRS[128+tid] + sRS[256+tid] + sRS[384+tid] + 1.0f;
  __syncthreads();
  const int bb = bh >> 4, h = bh & 15;
  #pragma unroll
  for (int rt=0;rt<2;rt++)
   #pragma unroll
   for (int ct=0;ct<4;ct++)
    #pragma unroll
    for (int r=0;r<4;r++){
      int n = wid*32 + rt*16 + g*4 + r;
      int d = ct*16 + l;
      float norm = sNorm[n];
      float vv = bf2f(V[(size_t)d*2048 + q0 + n]);
      float mv = accO[rt][ct][r]/norm - vv;
      Mb[((size_t)(bb*2048) + q0 + n)*1024 + h*64 + d] = f2bf(mv);
    }
}

// ---------- depthwise conv along n (KS=3, pad=1, per batch) ----------
__global__ __launch_bounds__(256) void conv_kernel(const u16* __restrict__ Hf, const float* __restrict__ w,
                                                   u16* __restrict__ Cv){
  int row = blockIdx.y;
  int n = row & 2047;
  int c0 = (blockIdx.x*256 + threadIdx.x)*8;
  us8v h0 = {0,0,0,0,0,0,0,0}, h2 = {0,0,0,0,0,0,0,0};
  us8v h1 = *(const us8v*)(Hf + (size_t)row*4096 + c0);
  if (n > 0)    h0 = *(const us8v*)(Hf + (size_t)(row-1)*4096 + c0);
  if (n < 2047) h2 = *(const us8v*)(Hf + (size_t)(row+1)*4096 + c0);
  us8v o;
  #pragma unroll
  for (int e=0;e<8;e++){
    int c = c0 + e;
    float acc = bf2f(h0[e])*w[c*3+0] + bf2f(h1[e])*w[c*3+1] + bf2f(h2[e])*w[c*3+2];
    o[e] = f2bf(acc);
  }
  *(us8v*)(Cv + (size_t)row*4096 + c0) = o;
}

extern "C" void kernel_launch(void* const* d_in, const int* in_sizes, int n_in,
                              void* d_out, int out_size, void* d_ws, size_t ws_size,
                              hipStream_t stream)
{
  const float* Q_in  = (const float*)d_in[0];
  const float* X     = (const float*)d_in[1];
  const float* Wq    = (const float*)d_in[2];
  const float* Wk    = (const float*)d_in[3];
  const float* Wv    = (const float*)d_in[4];
  const float* Wo    = (const float*)d_in[5];
  const float* Wup   = (const float*)d_in[6];
  const float* convw = (const float*)d_in[7];
  const float* Wdown = (const float*)d_in[8];
  const float* g1    = (const float*)d_in[9];
  const float* b1    = (const float*)d_in[10];
  const float* g2    = (const float*)d_in[11];
  const float* b2    = (const float*)d_in[12];
  const float* dt    = (const float*)d_in[13];
  float* out = (float*)d_out;

  char* ws = (char*)d_ws;
  const size_t MB = (size_t)1 << 20;
  u16* HcB   = (u16*)(ws + 0*MB);     // 8MB  (dead after QKV gemm)
  u16* WqkvT = (u16*)(ws + 8*MB);     // 6MB  (dead after QKV gemm)
  u16* WoT   = (u16*)(ws + 14*MB);    // 2MB  (dead after Wo gemm)
  u16* PhiQ  = (u16*)(ws + 16*MB);    // 8MB  } contiguous: PhiQ,PhiK,Vt (dead after attn)
  u16* Vt    = (u16*)(ws + 32*MB);    // 8MB
  u16* Mb    = (u16*)(ws + 40*MB);    // 8MB  (dead after Wo gemm)
  u16* Po    = (u16*)(ws + 48*MB);    // 16MB 2x bf16 partials (dead after ln2)
  u16* WupT  = (u16*)(ws + 80*MB);    // 16MB
  u16* WdT   = (u16*)(ws + 96*MB);    // 8MB
  float* Qint = (float*)(ws + 104*MB);// 16MB
  u16* Qn2   = (u16*)(ws + 120*MB);   // 8MB  (dead after Wup gemm)
  u16* Hf    = (u16*)(ws + 0*MB);     // 32MB (written after Wup gemm; old region dead)
  u16* Cv    = (u16*)(ws + 40*MB);    // 32MB (over Mb+Po, both dead by conv)
  u16* Pd    = (u16*)(ws + 0*MB);     // 16MB 2x bf16 partials (over Hf, dead after conv)
  u16* PhiK  = PhiQ + 4194304;

  // transposes + ln1 fused
  tr_all<<<20480, dim3(32, 8), 0, stream>>>(Wq, Wk, Wv, Wo, Wup, Wdown,
                                            WqkvT, WoT, WupT, WdT,
                                            Q_in, X, g1, b1, HcB);

  // fused QKV projection: [4096][1024] @ [3072][1024]^T
  gemm_qkv<<<dim3(32, 24), 256, 0, stream>>>(HcB, WqkvT, PhiQ);

  attn_kernel<<<dim3(16, 32), 256, 0, stream>>>(PhiQ, PhiK, Vt, Mb);

  // Wo projection, split-K=2 -> bf16 partials
  gemm_part<<<dim3(32, 8, 2), 256, 0, stream>>>(Mb, WoT, 1024, 1024, 512, Po);

  // Qint = Q_in + softplus(dt)*(Po0+Po1); Qn2 = LN(Qint)
  ln2_kernel<<<4096, 256, 0, stream>>>(Po, Q_in, dt, g2, b2, Qint, Qn2);

  // Wup with fused silu(G)*U epilogue -> Hf [4096][4096], 256x256 tiles, 4-phase fine pipeline
  gemm_wide_up<<<512, 512, 0, stream>>>(Qn2, WupT, Hf);

  conv_kernel<<<dim3(2, 4096), 256, 0, stream>>>(Hf, convw, Cv);

  // Wdown split-K=2 -> bf16 partials, then out = Qint + Pd0 + Pd1
  gemm_part<<<dim3(32, 8, 2), 256, 0, stream>>>(Cv, WdT, 1024, 4096, 2048, Pd);
  reduce_out<<<4096, 256, 0, stream>>>(Qint, Pd, out);
}

// Round 4
// 401.767 us; speedup vs baseline: 1.0254x; 1.0254x over previous
//
#include <hip/hip_runtime.h>

typedef unsigned short u16;
typedef __attribute__((ext_vector_type(8))) __bf16 bf16x8;
typedef __attribute__((ext_vector_type(4))) float f32x4;
typedef __attribute__((ext_vector_type(8))) unsigned short us8v;

__device__ __forceinline__ u16 f2bf(float x){
  union { float f; unsigned u; } v; v.f = x;
  unsigned r = v.u + 0x7fffu + ((v.u >> 16) & 1u);
  return (u16)(r >> 16);
}
__device__ __forceinline__ float bf2f(u16 h){
  union { unsigned u; float f; } v; v.u = ((unsigned)h) << 16;
  return v.f;
}
// async global->LDS, 16B per lane. lds ptr must be wave-uniform; HW writes base + lane*16.
__device__ __forceinline__ void gld16(const void* g, void* l){
  __builtin_amdgcn_global_load_lds((const __attribute__((address_space(1))) unsigned int*)g,
                                   (__attribute__((address_space(3))) unsigned int*)l, 16, 0, 0);
}

// ---------- weight transposes + ln1 in ONE kernel ----------
// 64x64 transpose tiles, fully coalesced: reads 256B/row (16 lanes x float4),
// writes 128B/out-row (16 lanes x ushort4). LDS t[64][65] fp32: stride-65 gives
// 2-way bank aliasing on both the row-write and column-read phases (free, m136).
// blocks 0..1023: Wq/Wk/Wv/Wo; 1024..3071: Wup (G/U interleave); 3072..4095: Wdown;
// blocks 4096..8191: ln1 rows (Hc = LN(Q_in)*g1+b1 + X)
__global__ __launch_bounds__(256) void tr_all(
    const float* __restrict__ Wq, const float* __restrict__ Wk,
    const float* __restrict__ Wv, const float* __restrict__ Wo,
    const float* __restrict__ Wup, const float* __restrict__ Wdown,
    u16* __restrict__ WqkvT, u16* __restrict__ WoT,
    u16* __restrict__ WupT, u16* __restrict__ WdT,
    const float* __restrict__ Qin, const float* __restrict__ X,
    const float* __restrict__ g1, const float* __restrict__ b1,
    u16* __restrict__ HcB)
{
  __shared__ float t[64][65];
  const int tid = threadIdx.x;
  const int id = blockIdx.x;
  if (id >= 4096){
    int row = id - 4096;
    const float4 x = ((const float4*)(Qin + (size_t)row*1024))[tid];
    float s = x.x + x.y + x.z + x.w;
    float sq = x.x*x.x + x.y*x.y + x.z*x.z + x.w*x.w;
    #pragma unroll
    for (int o=32;o>0;o>>=1){ s += __shfl_xor(s, o); sq += __shfl_xor(sq, o); }
    __shared__ float ss[4], ssq[4];
    int wid = tid>>6;
    if ((tid&63)==0){ ss[wid]=s; ssq[wid]=sq; }
    __syncthreads();
    s = ss[0]+ss[1]+ss[2]+ss[3]; sq = ssq[0]+ssq[1]+ssq[2]+ssq[3];
    float mu = s*(1.0f/1024.0f);
    float var = sq*(1.0f/1024.0f) - mu*mu;
    float rstd = rsqrtf(var + 1e-5f);
    float4 xx = ((const float4*)(X + (size_t)row*1024))[tid];
    float4 gv = ((const float4*)g1)[tid];
    float4 bv = ((const float4*)b1)[tid];
    ushort4 o;
    o.x = f2bf((x.x-mu)*rstd*gv.x + bv.x + xx.x);
    o.y = f2bf((x.y-mu)*rstd*gv.y + bv.y + xx.y);
    o.z = f2bf((x.z-mu)*rstd*gv.z + bv.z + xx.z);
    o.w = f2bf((x.w-mu)*rstd*gv.w + bv.w + xx.w);
    ((ushort4*)(HcB + (size_t)row*1024))[tid] = o;
    return;
  }
  const float* S; u16* D; int ldS; size_t ldD; int r0, c0; bool up = false;
  if (id < 1024){
    int w = id >> 8, b = id & 255;
    S = (w==0)?Wq:(w==1)?Wk:(w==2)?Wv:Wo;
    D = (w==3)? WoT : (WqkvT + (size_t)w*1048576);
    ldS = 1024; ldD = 1024;
    c0 = (b & 15)*64; r0 = (b >> 4)*64;
  } else if (id < 3072){
    int b = id - 1024;
    S = Wup; D = WupT; ldS = 8192; ldD = 1024; up = true;
    c0 = (b & 127)*64; r0 = (b >> 7)*64;
  } else {
    int b = id - 3072;
    S = Wdown; D = WdT; ldS = 1024; ldD = 4096;
    c0 = (b & 15)*64; r0 = (b >> 4)*64;
  }
  // read phase: 16 rows/iter, each row = 16 lanes x float4 = 256B contiguous
  {
    int cr = tid >> 4, cc = (tid & 15)*4;
    #pragma unroll
    for (int j=0;j<4;j++){
      int row = cr + 16*j;
      float4 v = *(const float4*)(S + (size_t)(r0+row)*ldS + c0 + cc);
      t[row][cc+0] = v.x; t[row][cc+1] = v.y; t[row][cc+2] = v.z; t[row][cc+3] = v.w;
    }
  }
  __syncthreads();
  // write phase: out-row oc = c0+ocp gets S[r0+x][oc]; 16 lanes x ushort4 = 128B/row
  {
    int p = tid & 15, rg = tid >> 4;
    #pragma unroll
    for (int k=0;k<4;k++){
      int ocp = rg + 16*k;
      int oc = c0 + ocp;
      ushort4 o;
      o.x = f2bf(t[4*p+0][ocp]);
      o.y = f2bf(t[4*p+1][ocp]);
      o.z = f2bf(t[4*p+2][ocp]);
      o.w = f2bf(t[4*p+3][ocp]);
      size_t orow;
      if (up) orow = (oc < 4096) ? (size_t)((oc>>4)*32 + (oc&15))
                                 : (size_t)(((oc-4096)>>4)*32 + 16 + (oc&15));
      else    orow = (size_t)oc;
      *(ushort4*)(D + orow*ldD + r0 + 4*p) = o;
    }
  }
}

// ---------- ln2: Qint = Q_in + softplus(dt)*(P0+P1); Qn2 = LN(Qint)*g+b (bf16 partials) ----------
__global__ __launch_bounds__(256) void ln2_kernel(const u16* __restrict__ P,
    const float* __restrict__ Qin, const float* __restrict__ dtp,
    const float* __restrict__ g, const float* __restrict__ b,
    float* __restrict__ Qint, u16* __restrict__ Qn2){
  int row = blockIdx.x, tid = threadIdx.x;
  float sp = log1pf(__expf(dtp[0]));
  size_t off = (size_t)row*1024;
  ushort4 p0 = ((const ushort4*)(P + off))[tid];
  ushort4 p1 = ((const ushort4*)(P + 4194304 + off))[tid];
  float4 q  = ((const float4*)(Qin + off))[tid];
  float4 x;
  x.x = q.x + sp*(bf2f(p0.x)+bf2f(p1.x)); x.y = q.y + sp*(bf2f(p0.y)+bf2f(p1.y));
  x.z = q.z + sp*(bf2f(p0.z)+bf2f(p1.z)); x.w = q.w + sp*(bf2f(p0.w)+bf2f(p1.w));
  ((float4*)(Qint + off))[tid] = x;
  float s = x.x + x.y + x.z + x.w;
  float sq = x.x*x.x + x.y*x.y + x.z*x.z + x.w*x.w;
  #pragma unroll
  for (int o=32;o>0;o>>=1){ s += __shfl_xor(s, o); sq += __shfl_xor(sq, o); }
  __shared__ float ss[4], ssq[4];
  int wid = tid>>6;
  if ((tid&63)==0){ ss[wid]=s; ssq[wid]=sq; }
  __syncthreads();
  s = ss[0]+ss[1]+ss[2]+ss[3]; sq = ssq[0]+ssq[1]+ssq[2]+ssq[3];
  float mu = s*(1.0f/1024.0f);
  float var = sq*(1.0f/1024.0f) - mu*mu;
  float rstd = rsqrtf(var + 1e-5f);
  float4 gv = ((const float4*)g)[tid];
  float4 bv = ((const float4*)b)[tid];
  ushort4 o;
  o.x = f2bf((x.x-mu)*rstd*gv.x + bv.x);
  o.y = f2bf((x.y-mu)*rstd*gv.y + bv.y);
  o.z = f2bf((x.z-mu)*rstd*gv.z + bv.z);
  o.w = f2bf((x.w-mu)*rstd*gv.w + bv.w);
  ((ushort4*)(Qn2 + off))[tid] = o;
}

// ---------- fused QKV GEMM (BK=64), A[4096][1024] @ WqkvT[3072][1024]^T ----------
__global__ __launch_bounds__(256, 3) void gemm_qkv(
    const u16* __restrict__ A, const u16* __restrict__ Bt, void* __restrict__ Op)
{
  __shared__ u16 As[128*64];
  __shared__ u16 Bs[128*64];
  const int tid = threadIdx.x, wid = tid>>6, lane = tid&63;
  const int g = lane>>4, l = lane&15, l7 = l&7;
  const int row0 = blockIdx.x*128, col0 = blockIdx.y*128;
  const int wr = (wid&1)*64, wc = (wid>>1)*64;
  f32x4 acc[4][4] = {};
  for (int k0 = 0; k0 < 1024; k0 += 64){
    __syncthreads();
    #pragma unroll
    for (int i=0;i<4;i++){
      int ch0 = i*256 + wid*64;
      int ch = ch0 + lane;
      int r = ch >> 3, c = ch & 7;
      int cs = c ^ (r & 7);     // XOR source swizzle -> conflict-free frag reads
      gld16(A  + (size_t)(row0+r)*1024 + k0 + cs*8, (char*)As + ch0*16);
      gld16(Bt + (size_t)(col0+r)*1024 + k0 + cs*8, (char*)Bs + ch0*16);
    }
    __syncthreads();
    #pragma unroll
    for (int kk=0; kk<2; kk++){
      bf16x8 a[4], b[4];
      #pragma unroll
      for (int i=0;i<4;i++) a[i] = *(const bf16x8*)(As + (wr + i*16 + l)*64 + (((kk*4+g)^l7)*8));
      #pragma unroll
      for (int j=0;j<4;j++) b[j] = *(const bf16x8*)(Bs + (wc + j*16 + l)*64 + (((kk*4+g)^l7)*8));
      #pragma unroll
      for (int i=0;i<4;i++)
        #pragma unroll
        for (int j=0;j<4;j++)
          acc[i][j] = __builtin_amdgcn_mfma_f32_16x16x32_bf16(a[i], b[j], acc[i][j], 0, 0, 0);
    }
  }
  u16* P = (u16*)Op;
  #pragma unroll
  for (int i=0;i<4;i++)
   #pragma unroll
   for (int j=0;j<4;j++){
     int col = col0 + wc + j*16 + l;
     int qk = col >> 10, c = col & 1023;
     int h = c >> 6, d = c & 63;
     int rowb = row0 + wr + i*16 + g*4;
     int bb = rowb >> 11, n = rowb & 2047;
     if (qk == 2){
       ushort4 vs;
       vs.x = f2bf(acc[i][j][0]); vs.y = f2bf(acc[i][j][1]);
       vs.z = f2bf(acc[i][j][2]); vs.w = f2bf(acc[i][j][3]);
       *(ushort4*)(P + (size_t)8388608 + (((size_t)(bb*16 + h))*64 + d)*2048 + n) = vs;
     } else {
       #pragma unroll
       for (int r=0;r<4;r++){
         float v = acc[i][j][r];
         float phi = v > 0.f ? v + 1.f : __expf(v);
         P[(size_t)qk*4194304 + (((size_t)(bb*16 + h))*2048 + (n+r))*64 + d] = f2bf(phi);
       }
     }
   }
}

// ---------- wide-tile GEMM for Wup (BK=64): 256x128 tile, 128x64/wave, fused silu(G)*U.
// Structure note: 48KB LDS -> 2 blocks/CU; the second resident block's MFMA covers this
// block's stage/barrier stalls (m114 implicit overlap). Deep 1-block/CU pipelines (r1/r3)
// measured SLOWER here (87/75.4 vs 70.4 us) because K=1024 = only 16 K-tiles.
__global__ __launch_bounds__(256, 2) void gemm_wide_up(
    const u16* __restrict__ A, const u16* __restrict__ Bt, u16* __restrict__ Op)
{
  __shared__ u16 As[256*64];   // 32KB
  __shared__ u16 Bs[128*64];   // 16KB
  const int tid = threadIdx.x, wid = tid>>6, lane = tid&63;
  const int g = lane>>4, l = lane&15, l7 = l&7;
  const int bid = blockIdx.x;
  const int bx = bid & 15;
  const int by = (bid>>7)*8 + ((bid>>4) & 7);
  const int row0 = bx*256, col0 = by*128;
  const int wr = (wid&1)*128, wc = (wid>>1)*64;
  f32x4 acc[8][4] = {};
  for (int k0 = 0; k0 < 1024; k0 += 64){
    __syncthreads();
    #pragma unroll
    for (int i=0;i<8;i++){
      int ch0 = i*256 + wid*64;
      int ch = ch0 + lane;
      int r = ch >> 3, c = ch & 7;
      int cs = c ^ (r & 7);
      gld16(A + (size_t)(row0+r)*1024 + k0 + cs*8, (char*)As + ch0*16);
    }
    #pragma unroll
    for (int i=0;i<4;i++){
      int ch0 = i*256 + wid*64;
      int ch = ch0 + lane;
      int r = ch >> 3, c = ch & 7;
      int cs = c ^ (r & 7);
      gld16(Bt + (size_t)(col0+r)*1024 + k0 + cs*8, (char*)Bs + ch0*16);
    }
    __syncthreads();
    #pragma unroll
    for (int kk=0; kk<2; kk++){
      bf16x8 a[8], b[4];
      #pragma unroll
      for (int i=0;i<8;i++) a[i] = *(const bf16x8*)(As + (wr + i*16 + l)*64 + (((kk*4+g)^l7)*8));
      #pragma unroll
      for (int j=0;j<4;j++) b[j] = *(const bf16x8*)(Bs + (wc + j*16 + l)*64 + (((kk*4+g)^l7)*8));
      #pragma unroll
      for (int i=0;i<8;i++)
        #pragma unroll
        for (int j=0;j<4;j++)
          acc[i][j] = __builtin_amdgcn_mfma_f32_16x16x32_bf16(a[i], b[j], acc[i][j], 0, 0, 0);
    }
  }
  #pragma unroll
  for (int i=0;i<8;i++)
   #pragma unroll
   for (int jj=0;jj<4;jj+=2)
    #pragma unroll
    for (int r=0;r<4;r++){
      int row = row0 + wr + i*16 + g*4 + r;
      int pair = (col0 + wc + jj*16) >> 5;
      float G = acc[i][jj][r], U = acc[i][jj+1][r];
      float hf = G/(1.f+__expf(-G))*U;
      Op[(size_t)row*4096 + pair*16 + l] = f2bf(hf);
    }
}

// ---------- split-K GEMM (BK=64): bf16 partial per z-slice ----------
__global__ __launch_bounds__(256, 3) void gemm_part(
    const u16* __restrict__ A, const u16* __restrict__ Bt,
    int Nc, int K, int Ks, u16* __restrict__ Op)
{
  __shared__ u16 As[128*64];
  __shared__ u16 Bs[128*64];
  const int tid = threadIdx.x, wid = tid>>6, lane = tid&63;
  const int g = lane>>4, l = lane&15, l7 = l&7;
  const int row0 = blockIdx.x*128, col0 = blockIdx.y*128;
  const int kbase = blockIdx.z*Ks;
  const int wr = (wid&1)*64, wc = (wid>>1)*64;
  f32x4 acc[4][4] = {};
  for (int k0 = kbase; k0 < kbase + Ks; k0 += 64){
    __syncthreads();
    #pragma unroll
    for (int i=0;i<4;i++){
      int ch0 = i*256 + wid*64;
      int ch = ch0 + lane;
      int r = ch >> 3, c = ch & 7;
      int cs = c ^ (r & 7);
      gld16(A  + (size_t)(row0+r)*K + k0 + cs*8, (char*)As + ch0*16);
      gld16(Bt + (size_t)(col0+r)*K + k0 + cs*8, (char*)Bs + ch0*16);
    }
    __syncthreads();
    #pragma unroll
    for (int kk=0; kk<2; kk++){
      bf16x8 a[4], b[4];
      #pragma unroll
      for (int i=0;i<4;i++) a[i] = *(const bf16x8*)(As + (wr + i*16 + l)*64 + (((kk*4+g)^l7)*8));
      #pragma unroll
      for (int j=0;j<4;j++) b[j] = *(const bf16x8*)(Bs + (wc + j*16 + l)*64 + (((kk*4+g)^l7)*8));
      #pragma unroll
      for (int i=0;i<4;i++)
        #pragma unroll
        for (int j=0;j<4;j++)
          acc[i][j] = __builtin_amdgcn_mfma_f32_16x16x32_bf16(a[i], b[j], acc[i][j], 0, 0, 0);
    }
  }
  u16* P = Op + (size_t)blockIdx.z*4194304;
  #pragma unroll
  for (int i=0;i<4;i++)
   #pragma unroll
   for (int j=0;j<4;j++)
    #pragma unroll
    for (int r=0;r<4;r++){
      int row = row0 + wr + i*16 + g*4 + r;
      int col = col0 + wc + j*16 + l;
      P[(size_t)row*Nc + col] = f2bf(acc[i][j][r]);
    }
}

// ---------- out = Qint + Pd0 + Pd1 (bf16 partials) ----------
__global__ __launch_bounds__(256) void reduce_out(const float* __restrict__ Qint,
    const u16* __restrict__ P, float* __restrict__ out){
  size_t i = (size_t)blockIdx.x*256 + threadIdx.x;
  float4 a  = ((const float4*)Qint)[i];
  ushort4 p0 = ((const ushort4*)P)[i];
  ushort4 p1 = ((const ushort4*)(P + 4194304))[i];
  float4 o;
  o.x = a.x + bf2f(p0.x) + bf2f(p1.x); o.y = a.y + bf2f(p0.y) + bf2f(p1.y);
  o.z = a.z + bf2f(p0.z) + bf2f(p1.z); o.w = a.w + bf2f(p0.w) + bf2f(p1.w);
  ((float4*)out)[i] = o;
}

// ---------- linear attention with relu^2, flash-style ----------
// Q-fragments in registers (loop-invariant). LDS = sK 16 + sV 16 + sW 32 = 64KB -> 2 blocks/CU.
__global__ __launch_bounds__(256, 2) void attn_kernel(
    const u16* __restrict__ PhiQ, const u16* __restrict__ PhiK,
    const u16* __restrict__ Vt, u16* __restrict__ Mb)
{
  __shared__ u16 sK[2][128][32];
  __shared__ u16 sV[4][64][32];
  __shared__ u16 sW[128*128];
  const int tid = threadIdx.x, wid = tid>>6, lane = tid&63;
  const int g = lane>>4, l = lane&15;
  const int l3 = l & 3;
  const int q0 = blockIdx.x*128, bh = blockIdx.y;
  const u16* Q  = PhiQ + (size_t)bh*2048*64;
  const u16* Kb = PhiK + (size_t)bh*2048*64;
  const u16* V  = Vt   + (size_t)bh*64*2048;
  bf16x8 bq[8][2];
  #pragma unroll
  for (int ct=0;ct<8;ct++)
    #pragma unroll
    for (int ks=0;ks<2;ks++)
      bq[ct][ks] = *(const bf16x8*)(Q + (size_t)(q0 + ct*16 + l)*64 + ks*32 + g*8);
  f32x4 accO[2][4] = {};
  float rsum[8] = {0.f,0.f,0.f,0.f,0.f,0.f,0.f,0.f};
  for (int m0 = 0; m0 < 2048; m0 += 128){
    __syncthreads();
    #pragma unroll
    for (int ks=0; ks<2; ks++)
      #pragma unroll
      for (int i=0;i<2;i++){
        int ch0 = i*256 + wid*64;
        int ch = ch0 + lane;
        int r = ch >> 2, q = ch & 3;
        int qs = q ^ (r & 3);
        gld16(Kb + (size_t)(m0+r)*64 + ks*32 + qs*8, (char*)&sK[ks][0][0] + ch0*16);
      }
    #pragma unroll
    for (int c=0; c<4; c++){
      int ch0 = wid*64;
      int ch = ch0 + lane;
      int d = ch >> 2, q = ch & 3;
      int qs = q ^ (d & 3);
      gld16(V + (size_t)d*2048 + m0 + c*32 + qs*8, (char*)&sV[c][0][0] + ch0*16);
    }
    __syncthreads();
    f32x4 st[2][8] = {};
    bf16x8 ak[2][2];
    #pragma unroll
    for (int rt=0;rt<2;rt++)
      #pragma unroll
      for (int ks=0;ks<2;ks++)
        ak[rt][ks] = *(const bf16x8*)&sK[ks][wid*32 + rt*16 + l][(g^l3)*8];
    #pragma unroll
    for (int ct=0;ct<8;ct++){
      #pragma unroll
      for (int ks=0;ks<2;ks++){
        st[0][ct] = __builtin_amdgcn_mfma_f32_16x16x32_bf16(ak[0][ks], bq[ct][ks], st[0][ct], 0,0,0);
        st[1][ct] = __builtin_amdgcn_mfma_f32_16x16x32_bf16(ak[1][ks], bq[ct][ks], st[1][ct], 0,0,0);
      }
    }
    #pragma unroll
    for (int ct=0;ct<8;ct++){
      float part = 0.f;
      #pragma unroll
      for (int rt=0;rt<2;rt++){
        float s0 = fmaxf(st[rt][ct][0], 0.f), s1 = fmaxf(st[rt][ct][1], 0.f);
        float s2 = fmaxf(st[rt][ct][2], 0.f), s3 = fmaxf(st[rt][ct][3], 0.f);
        float w0 = s0*s0, w1 = s1*s1, w2 = s2*s2, w3 = s3*s3;
        part += w0 + w1 + w2 + w3;
        int n = ct*16 + l;
        int mblk = wid*4 + rt*2 + (g>>1);
        ushort4 w4;
        w4.x = f2bf(w0); w4.y = f2bf(w1); w4.z = f2bf(w2); w4.w = f2bf(w3);
        *(ushort4*)(sW + n*128 + ((mblk ^ l)*8) + (g&1)*4) = w4;
      }
      rsum[ct] += part;
    }
    __syncthreads();
    #pragma unroll
    for (int ks=0;ks<4;ks++){
      int n0 = wid*32 + l, n1 = wid*32 + 16 + l;
      bf16x8 aw0 = *(const bf16x8*)(sW + n0*128 + (((ks*4+g) ^ (n0&15))*8));
      bf16x8 aw1 = *(const bf16x8*)(sW + n1*128 + (((ks*4+g) ^ (n1&15))*8));
      #pragma unroll
      for (int ct=0;ct<4;ct++){
        bf16x8 bv = *(const bf16x8*)&sV[ks][ct*16 + l][(g^l3)*8];
        accO[0][ct] = __builtin_amdgcn_mfma_f32_16x16x32_bf16(aw0, bv, accO[0][ct], 0,0,0);
        accO[1][ct] = __builtin_amdgcn_mfma_f32_16x16x32_bf16(aw1, bv, accO[1][ct], 0,0,0);
      }
    }
  }
  __syncthreads();
  float* sRS = (float*)sW;
  float* sNorm = ((float*)sW) + 512;
  #pragma unroll
  for (int ct=0;ct<8;ct++){
    float v = rsum[ct];
    v += __shfl_xor(v, 16);
    v += __shfl_xor(v, 32);
    rsum[ct] = v;
  }
  if (g == 0){
    #pragma unroll
    for (int ct=0;ct<8;ct++) sRS[wid*128 + ct*16 + l] = rsum[ct];
  }
  __syncthreads();
  if (tid < 128) sNorm[tid] = sRS[tid] + sRS[128+tid] + sRS[256+tid] + sRS[384+tid] + 1.0f;
  __syncthreads();
  const int bb = bh >> 4, h = bh & 15;
  #pragma unroll
  for (int rt=0;rt<2;rt++)
   #pragma unroll
   for (int ct=0;ct<4;ct++)
    #pragma unroll
    for (int r=0;r<4;r++){
      int n = wid*32 + rt*16 + g*4 + r;
      int d = ct*16 + l;
      float norm = sNorm[n];
      float vv = bf2f(V[(size_t)d*2048 + q0 + n]);
      float mv = accO[rt][ct][r]/norm - vv;
      Mb[((size_t)(bb*2048) + q0 + n)*1024 + h*64 + d] = f2bf(mv);
    }
}

// ---------- depthwise conv along n (KS=3, pad=1, per batch) ----------
__global__ __launch_bounds__(256) void conv_kernel(const u16* __restrict__ Hf, const float* __restrict__ w,
                                                   u16* __restrict__ Cv){
  int row = blockIdx.y;
  int n = row & 2047;
  int c0 = (blockIdx.x*256 + threadIdx.x)*8;
  us8v h0 = {0,0,0,0,0,0,0,0}, h2 = {0,0,0,0,0,0,0,0};
  us8v h1 = *(const us8v*)(Hf + (size_t)row*4096 + c0);
  if (n > 0)    h0 = *(const us8v*)(Hf + (size_t)(row-1)*4096 + c0);
  if (n < 2047) h2 = *(const us8v*)(Hf + (size_t)(row+1)*4096 + c0);
  us8v o;
  #pragma unroll
  for (int e=0;e<8;e++){
    int c = c0 + e;
    float acc = bf2f(h0[e])*w[c*3+0] + bf2f(h1[e])*w[c*3+1] + bf2f(h2[e])*w[c*3+2];
    o[e] = f2bf(acc);
  }
  *(us8v*)(Cv + (size_t)row*4096 + c0) = o;
}

extern "C" void kernel_launch(void* const* d_in, const int* in_sizes, int n_in,
                              void* d_out, int out_size, void* d_ws, size_t ws_size,
                              hipStream_t stream)
{
  const float* Q_in  = (const float*)d_in[0];
  const float* X     = (const float*)d_in[1];
  const float* Wq    = (const float*)d_in[2];
  const float* Wk    = (const float*)d_in[3];
  const float* Wv    = (const float*)d_in[4];
  const float* Wo    = (const float*)d_in[5];
  const float* Wup   = (const float*)d_in[6];
  const float* convw = (const float*)d_in[7];
  const float* Wdown = (const float*)d_in[8];
  const float* g1    = (const float*)d_in[9];
  const float* b1    = (const float*)d_in[10];
  const float* g2    = (const float*)d_in[11];
  const float* b2    = (const float*)d_in[12];
  const float* dt    = (const float*)d_in[13];
  float* out = (float*)d_out;

  char* ws = (char*)d_ws;
  const size_t MB = (size_t)1 << 20;
  u16* HcB   = (u16*)(ws + 0*MB);     // 8MB  (dead after QKV gemm)
  u16* WqkvT = (u16*)(ws + 8*MB);     // 6MB  (dead after QKV gemm)
  u16* WoT   = (u16*)(ws + 14*MB);    // 2MB  (dead after Wo gemm)
  u16* PhiQ  = (u16*)(ws + 16*MB);    // 8MB  } contiguous: PhiQ,PhiK,Vt (dead after attn)
  u16* Vt    = (u16*)(ws + 32*MB);    // 8MB
  u16* Mb    = (u16*)(ws + 40*MB);    // 8MB  (dead after Wo gemm)
  u16* Po    = (u16*)(ws + 48*MB);    // 16MB 2x bf16 partials (dead after ln2)
  u16* WupT  = (u16*)(ws + 80*MB);    // 16MB
  u16* WdT   = (u16*)(ws + 96*MB);    // 8MB
  float* Qint = (float*)(ws + 104*MB);// 16MB
  u16* Qn2   = (u16*)(ws + 120*MB);   // 8MB  (dead after Wup gemm)
  u16* Hf    = (u16*)(ws + 0*MB);     // 32MB (written after Wup gemm; old region dead)
  u16* Cv    = (u16*)(ws + 40*MB);    // 32MB (over Mb+Po, both dead by conv)
  u16* Pd    = (u16*)(ws + 0*MB);     // 16MB 2x bf16 partials (over Hf, dead after conv)
  u16* PhiK  = PhiQ + 4194304;

  // transposes (64x64 coalesced tiles) + ln1 fused
  tr_all<<<8192, 256, 0, stream>>>(Wq, Wk, Wv, Wo, Wup, Wdown,
                                   WqkvT, WoT, WupT, WdT,
                                   Q_in, X, g1, b1, HcB);

  // fused QKV projection: [4096][1024] @ [3072][1024]^T
  gemm_qkv<<<dim3(32, 24), 256, 0, stream>>>(HcB, WqkvT, PhiQ);

  attn_kernel<<<dim3(16, 32), 256, 0, stream>>>(PhiQ, PhiK, Vt, Mb);

  // Wo projection, split-K=2 -> bf16 partials
  gemm_part<<<dim3(32, 8, 2), 256, 0, stream>>>(Mb, WoT, 1024, 1024, 512, Po);

  // Qint = Q_in + softplus(dt)*(Po0+Po1); Qn2 = LN(Qint)
  ln2_kernel<<<4096, 256, 0, stream>>>(Po, Q_in, dt, g2, b2, Qint, Qn2);

  // Wup with fused silu(G)*U epilogue -> Hf [4096][4096], wide 256x128 tiles, BK=64
  gemm_wide_up<<<1024, 256, 0, stream>>>(Qn2, WupT, Hf);

  conv_kernel<<<dim3(2, 4096), 256, 0, stream>>>(Hf, convw, Cv);

  // Wdown split-K=2 -> bf16 partials, then out = Qint + Pd0 + Pd1
  gemm_part<<<dim3(32, 8, 2), 256, 0, stream>>>(Cv, WdT, 1024, 4096, 2048, Pd);
  reduce_out<<<4096, 256, 0, stream>>>(Qint, Pd, out);
}

// Round 5
// 382.323 us; speedup vs baseline: 1.0776x; 1.0509x over previous
//
#include <hip/hip_runtime.h>

typedef unsigned short u16;
typedef __attribute__((ext_vector_type(8))) __bf16 bf16x8;
typedef __attribute__((ext_vector_type(4))) float f32x4;
typedef __attribute__((ext_vector_type(8))) unsigned short us8v;

__device__ __forceinline__ u16 f2bf(float x){
  union { float f; unsigned u; } v; v.f = x;
  unsigned r = v.u + 0x7fffu + ((v.u >> 16) & 1u);
  return (u16)(r >> 16);
}
__device__ __forceinline__ float bf2f(u16 h){
  union { unsigned u; float f; } v; v.u = ((unsigned)h) << 16;
  return v.f;
}
// packed bf16 convert: 2 floats -> 1 dword (RNE), 4 floats -> uint2. gfx950 has no builtin.
__device__ __forceinline__ uint2 pkbf4(float a, float b, float c, float d){
  uint2 r;
  asm("v_cvt_pk_bf16_f32 %0, %1, %2" : "=v"(r.x) : "v"(a), "v"(b));
  asm("v_cvt_pk_bf16_f32 %0, %1, %2" : "=v"(r.y) : "v"(c), "v"(d));
  return r;
}
// async global->LDS, 16B per lane. lds ptr must be wave-uniform; HW writes base + lane*16.
__device__ __forceinline__ void gld16(const void* g, void* l){
  __builtin_amdgcn_global_load_lds((const __attribute__((address_space(1))) unsigned int*)g,
                                   (__attribute__((address_space(3))) unsigned int*)l, 16, 0, 0);
}

// ---------- weight transposes + ln1 in ONE kernel ----------
// 64x64 transpose tiles, fully coalesced: reads 256B/row (16 lanes x float4),
// writes 128B/out-row (16 lanes x ushort4). LDS t[64][65] fp32: stride-65 gives
// 2-way bank aliasing on both phases (free, m136).
// blocks 0..1023: Wq/Wk/Wv/Wo; 1024..3071: Wup (G/U interleave); 3072..4095: Wdown;
// blocks 4096..8191: ln1 rows (Hc = LN(Q_in)*g1+b1 + X)
__global__ __launch_bounds__(256) void tr_all(
    const float* __restrict__ Wq, const float* __restrict__ Wk,
    const float* __restrict__ Wv, const float* __restrict__ Wo,
    const float* __restrict__ Wup, const float* __restrict__ Wdown,
    u16* __restrict__ WqkvT, u16* __restrict__ WoT,
    u16* __restrict__ WupT, u16* __restrict__ WdT,
    const float* __restrict__ Qin, const float* __restrict__ X,
    const float* __restrict__ g1, const float* __restrict__ b1,
    u16* __restrict__ HcB)
{
  __shared__ float t[64][65];
  const int tid = threadIdx.x;
  const int id = blockIdx.x;
  if (id >= 4096){
    int row = id - 4096;
    const float4 x = ((const float4*)(Qin + (size_t)row*1024))[tid];
    float s = x.x + x.y + x.z + x.w;
    float sq = x.x*x.x + x.y*x.y + x.z*x.z + x.w*x.w;
    #pragma unroll
    for (int o=32;o>0;o>>=1){ s += __shfl_xor(s, o); sq += __shfl_xor(sq, o); }
    __shared__ float ss[4], ssq[4];
    int wid = tid>>6;
    if ((tid&63)==0){ ss[wid]=s; ssq[wid]=sq; }
    __syncthreads();
    s = ss[0]+ss[1]+ss[2]+ss[3]; sq = ssq[0]+ssq[1]+ssq[2]+ssq[3];
    float mu = s*(1.0f/1024.0f);
    float var = sq*(1.0f/1024.0f) - mu*mu;
    float rstd = rsqrtf(var + 1e-5f);
    float4 xx = ((const float4*)(X + (size_t)row*1024))[tid];
    float4 gv = ((const float4*)g1)[tid];
    float4 bv = ((const float4*)b1)[tid];
    ((uint2*)(HcB + (size_t)row*1024))[tid] = pkbf4(
      (x.x-mu)*rstd*gv.x + bv.x + xx.x,
      (x.y-mu)*rstd*gv.y + bv.y + xx.y,
      (x.z-mu)*rstd*gv.z + bv.z + xx.z,
      (x.w-mu)*rstd*gv.w + bv.w + xx.w);
    return;
  }
  const float* S; u16* D; int ldS; size_t ldD; int r0, c0; bool up = false;
  if (id < 1024){
    int w = id >> 8, b = id & 255;
    S = (w==0)?Wq:(w==1)?Wk:(w==2)?Wv:Wo;
    D = (w==3)? WoT : (WqkvT + (size_t)w*1048576);
    ldS = 1024; ldD = 1024;
    c0 = (b & 15)*64; r0 = (b >> 4)*64;
  } else if (id < 3072){
    int b = id - 1024;
    S = Wup; D = WupT; ldS = 8192; ldD = 1024; up = true;
    c0 = (b & 127)*64; r0 = (b >> 7)*64;
  } else {
    int b = id - 3072;
    S = Wdown; D = WdT; ldS = 1024; ldD = 4096;
    c0 = (b & 15)*64; r0 = (b >> 4)*64;
  }
  {
    int cr = tid >> 4, cc = (tid & 15)*4;
    #pragma unroll
    for (int j=0;j<4;j++){
      int row = cr + 16*j;
      float4 v = *(const float4*)(S + (size_t)(r0+row)*ldS + c0 + cc);
      t[row][cc+0] = v.x; t[row][cc+1] = v.y; t[row][cc+2] = v.z; t[row][cc+3] = v.w;
    }
  }
  __syncthreads();
  {
    int p = tid & 15, rg = tid >> 4;
    #pragma unroll
    for (int k=0;k<4;k++){
      int ocp = rg + 16*k;
      int oc = c0 + ocp;
      uint2 o = pkbf4(t[4*p+0][ocp], t[4*p+1][ocp], t[4*p+2][ocp], t[4*p+3][ocp]);
      size_t orow;
      if (up) orow = (oc < 4096) ? (size_t)((oc>>4)*32 + (oc&15))
                                 : (size_t)(((oc-4096)>>4)*32 + 16 + (oc&15));
      else    orow = (size_t)oc;
      *(uint2*)(D + orow*ldD + r0 + 4*p) = o;
    }
  }
}

// ---------- ln2: Qint = Q_in + softplus(dt)*(P0+P1); Qn2 = LN(Qint)*g+b (bf16 partials) ----------
__global__ __launch_bounds__(256) void ln2_kernel(const u16* __restrict__ P,
    const float* __restrict__ Qin, const float* __restrict__ dtp,
    const float* __restrict__ g, const float* __restrict__ b,
    float* __restrict__ Qint, u16* __restrict__ Qn2){
  int row = blockIdx.x, tid = threadIdx.x;
  float sp = log1pf(__expf(dtp[0]));
  size_t off = (size_t)row*1024;
  ushort4 p0 = ((const ushort4*)(P + off))[tid];
  ushort4 p1 = ((const ushort4*)(P + 4194304 + off))[tid];
  float4 q  = ((const float4*)(Qin + off))[tid];
  float4 x;
  x.x = q.x + sp*(bf2f(p0.x)+bf2f(p1.x)); x.y = q.y + sp*(bf2f(p0.y)+bf2f(p1.y));
  x.z = q.z + sp*(bf2f(p0.z)+bf2f(p1.z)); x.w = q.w + sp*(bf2f(p0.w)+bf2f(p1.w));
  ((float4*)(Qint + off))[tid] = x;
  float s = x.x + x.y + x.z + x.w;
  float sq = x.x*x.x + x.y*x.y + x.z*x.z + x.w*x.w;
  #pragma unroll
  for (int o=32;o>0;o>>=1){ s += __shfl_xor(s, o); sq += __shfl_xor(sq, o); }
  __shared__ float ss[4], ssq[4];
  int wid = tid>>6;
  if ((tid&63)==0){ ss[wid]=s; ssq[wid]=sq; }
  __syncthreads();
  s = ss[0]+ss[1]+ss[2]+ss[3]; sq = ssq[0]+ssq[1]+ssq[2]+ssq[3];
  float mu = s*(1.0f/1024.0f);
  float var = sq*(1.0f/1024.0f) - mu*mu;
  float rstd = rsqrtf(var + 1e-5f);
  float4 gv = ((const float4*)g)[tid];
  float4 bv = ((const float4*)b)[tid];
  ((uint2*)(Qn2 + off))[tid] = pkbf4(
    (x.x-mu)*rstd*gv.x + bv.x, (x.y-mu)*rstd*gv.y + bv.y,
    (x.z-mu)*rstd*gv.z + bv.z, (x.w-mu)*rstd*gv.w + bv.w);
}

// ---------- fused QKV GEMM (BK=64), A[4096][1024] @ WqkvT[3072][1024]^T ----------
__global__ __launch_bounds__(256, 3) void gemm_qkv(
    const u16* __restrict__ A, const u16* __restrict__ Bt, void* __restrict__ Op)
{
  __shared__ u16 As[128*64];
  __shared__ u16 Bs[128*64];
  const int tid = threadIdx.x, wid = tid>>6, lane = tid&63;
  const int g = lane>>4, l = lane&15, l7 = l&7;
  const int row0 = blockIdx.x*128, col0 = blockIdx.y*128;
  const int wr = (wid&1)*64, wc = (wid>>1)*64;
  f32x4 acc[4][4] = {};
  for (int k0 = 0; k0 < 1024; k0 += 64){
    __syncthreads();
    #pragma unroll
    for (int i=0;i<4;i++){
      int ch0 = i*256 + wid*64;
      int ch = ch0 + lane;
      int r = ch >> 3, c = ch & 7;
      int cs = c ^ (r & 7);     // XOR source swizzle -> conflict-free frag reads
      gld16(A  + (size_t)(row0+r)*1024 + k0 + cs*8, (char*)As + ch0*16);
      gld16(Bt + (size_t)(col0+r)*1024 + k0 + cs*8, (char*)Bs + ch0*16);
    }
    __syncthreads();
    #pragma unroll
    for (int kk=0; kk<2; kk++){
      bf16x8 a[4], b[4];
      #pragma unroll
      for (int i=0;i<4;i++) a[i] = *(const bf16x8*)(As + (wr + i*16 + l)*64 + (((kk*4+g)^l7)*8));
      #pragma unroll
      for (int j=0;j<4;j++) b[j] = *(const bf16x8*)(Bs + (wc + j*16 + l)*64 + (((kk*4+g)^l7)*8));
      #pragma unroll
      for (int i=0;i<4;i++)
        #pragma unroll
        for (int j=0;j<4;j++)
          acc[i][j] = __builtin_amdgcn_mfma_f32_16x16x32_bf16(a[i], b[j], acc[i][j], 0, 0, 0);
    }
  }
  u16* P = (u16*)Op;
  #pragma unroll
  for (int i=0;i<4;i++)
   #pragma unroll
   for (int j=0;j<4;j++){
     int col = col0 + wc + j*16 + l;
     int qk = col >> 10, c = col & 1023;
     int h = c >> 6, d = c & 63;
     int rowb = row0 + wr + i*16 + g*4;
     int bb = rowb >> 11, n = rowb & 2047;
     if (qk == 2){
       *(uint2*)(P + (size_t)8388608 + (((size_t)(bb*16 + h))*64 + d)*2048 + n) =
         pkbf4(acc[i][j][0], acc[i][j][1], acc[i][j][2], acc[i][j][3]);
     } else {
       #pragma unroll
       for (int r=0;r<4;r++){
         float v = acc[i][j][r];
         float phi = v > 0.f ? v + 1.f : __expf(v);
         P[(size_t)qk*4194304 + (((size_t)(bb*16 + h))*2048 + (n+r))*64 + d] = f2bf(phi);
       }
     }
   }
}

// ---------- wide-tile GEMM for Wup (BK=64): 256x128 tile, 128x64/wave, fused silu(G)*U.
// 48KB LDS -> 2+ blocks/CU; resident-block MFMA covers stage/barrier stalls (m114).
// Deep 1-block/CU pipelines (r1/r3) measured SLOWER here (87/75.4 vs 70.4 us): K=1024 = 16 K-tiles.
__global__ __launch_bounds__(256, 2) void gemm_wide_up(
    const u16* __restrict__ A, const u16* __restrict__ Bt, u16* __restrict__ Op)
{
  __shared__ u16 As[256*64];   // 32KB
  __shared__ u16 Bs[128*64];   // 16KB
  const int tid = threadIdx.x, wid = tid>>6, lane = tid&63;
  const int g = lane>>4, l = lane&15, l7 = l&7;
  const int bid = blockIdx.x;
  const int bx = bid & 15;
  const int by = (bid>>7)*8 + ((bid>>4) & 7);
  const int row0 = bx*256, col0 = by*128;
  const int wr = (wid&1)*128, wc = (wid>>1)*64;
  f32x4 acc[8][4] = {};
  for (int k0 = 0; k0 < 1024; k0 += 64){
    __syncthreads();
    #pragma unroll
    for (int i=0;i<8;i++){
      int ch0 = i*256 + wid*64;
      int ch = ch0 + lane;
      int r = ch >> 3, c = ch & 7;
      int cs = c ^ (r & 7);
      gld16(A + (size_t)(row0+r)*1024 + k0 + cs*8, (char*)As + ch0*16);
    }
    #pragma unroll
    for (int i=0;i<4;i++){
      int ch0 = i*256 + wid*64;
      int ch = ch0 + lane;
      int r = ch >> 3, c = ch & 7;
      int cs = c ^ (r & 7);
      gld16(Bt + (size_t)(col0+r)*1024 + k0 + cs*8, (char*)Bs + ch0*16);
    }
    __syncthreads();
    #pragma unroll
    for (int kk=0; kk<2; kk++){
      bf16x8 a[8], b[4];
      #pragma unroll
      for (int i=0;i<8;i++) a[i] = *(const bf16x8*)(As + (wr + i*16 + l)*64 + (((kk*4+g)^l7)*8));
      #pragma unroll
      for (int j=0;j<4;j++) b[j] = *(const bf16x8*)(Bs + (wc + j*16 + l)*64 + (((kk*4+g)^l7)*8));
      #pragma unroll
      for (int i=0;i<8;i++)
        #pragma unroll
        for (int j=0;j<4;j++)
          acc[i][j] = __builtin_amdgcn_mfma_f32_16x16x32_bf16(a[i], b[j], acc[i][j], 0, 0, 0);
    }
  }
  #pragma unroll
  for (int i=0;i<8;i++)
   #pragma unroll
   for (int jj=0;jj<4;jj+=2)
    #pragma unroll
    for (int r=0;r<4;r++){
      int row = row0 + wr + i*16 + g*4 + r;
      int pair = (col0 + wc + jj*16) >> 5;
      float G = acc[i][jj][r], U = acc[i][jj+1][r];
      float hf = G/(1.f+__expf(-G))*U;
      Op[(size_t)row*4096 + pair*16 + l] = f2bf(hf);
    }
}

// ---------- wide-tile split-K GEMM for Wdown: 256x128 tile, K=4096 via 4 z-slices of 1024.
// Same staging/compute structure as gemm_wide_up (981 TF measured in-pipeline) vs the
// 128^2 gemm_part structure (~875 TF). Grid (16,8,4)=512 blocks = 2/CU.
__global__ __launch_bounds__(256, 2) void gemm_wide_down(
    const u16* __restrict__ A, const u16* __restrict__ Bt, u16* __restrict__ Op)
{
  __shared__ u16 As[256*64];   // 32KB
  __shared__ u16 Bs[128*64];   // 16KB
  const int tid = threadIdx.x, wid = tid>>6, lane = tid&63;
  const int g = lane>>4, l = lane&15, l7 = l&7;
  const int row0 = blockIdx.x*256, col0 = blockIdx.y*128;
  const int kbase = blockIdx.z*1024;
  const int wr = (wid&1)*128, wc = (wid>>1)*64;
  f32x4 acc[8][4] = {};
  for (int k0 = kbase; k0 < kbase + 1024; k0 += 64){
    __syncthreads();
    #pragma unroll
    for (int i=0;i<8;i++){
      int ch0 = i*256 + wid*64;
      int ch = ch0 + lane;
      int r = ch >> 3, c = ch & 7;
      int cs = c ^ (r & 7);
      gld16(A + (size_t)(row0+r)*4096 + k0 + cs*8, (char*)As + ch0*16);
    }
    #pragma unroll
    for (int i=0;i<4;i++){
      int ch0 = i*256 + wid*64;
      int ch = ch0 + lane;
      int r = ch >> 3, c = ch & 7;
      int cs = c ^ (r & 7);
      gld16(Bt + (size_t)(col0+r)*4096 + k0 + cs*8, (char*)Bs + ch0*16);
    }
    __syncthreads();
    #pragma unroll
    for (int kk=0; kk<2; kk++){
      bf16x8 a[8], b[4];
      #pragma unroll
      for (int i=0;i<8;i++) a[i] = *(const bf16x8*)(As + (wr + i*16 + l)*64 + (((kk*4+g)^l7)*8));
      #pragma unroll
      for (int j=0;j<4;j++) b[j] = *(const bf16x8*)(Bs + (wc + j*16 + l)*64 + (((kk*4+g)^l7)*8));
      #pragma unroll
      for (int i=0;i<8;i++)
        #pragma unroll
        for (int j=0;j<4;j++)
          acc[i][j] = __builtin_amdgcn_mfma_f32_16x16x32_bf16(a[i], b[j], acc[i][j], 0, 0, 0);
    }
  }
  u16* P = Op + (size_t)blockIdx.z*4194304;
  #pragma unroll
  for (int i=0;i<8;i++)
   #pragma unroll
   for (int j=0;j<4;j++)
    #pragma unroll
    for (int r=0;r<4;r++){
      int row = row0 + wr + i*16 + g*4 + r;
      int col = col0 + wc + j*16 + l;
      P[(size_t)row*1024 + col] = f2bf(acc[i][j][r]);
    }
}

// ---------- split-K GEMM (BK=64): bf16 partial per z-slice (used for Wo) ----------
__global__ __launch_bounds__(256, 3) void gemm_part(
    const u16* __restrict__ A, const u16* __restrict__ Bt,
    int Nc, int K, int Ks, u16* __restrict__ Op)
{
  __shared__ u16 As[128*64];
  __shared__ u16 Bs[128*64];
  const int tid = threadIdx.x, wid = tid>>6, lane = tid&63;
  const int g = lane>>4, l = lane&15, l7 = l&7;
  const int row0 = blockIdx.x*128, col0 = blockIdx.y*128;
  const int kbase = blockIdx.z*Ks;
  const int wr = (wid&1)*64, wc = (wid>>1)*64;
  f32x4 acc[4][4] = {};
  for (int k0 = kbase; k0 < kbase + Ks; k0 += 64){
    __syncthreads();
    #pragma unroll
    for (int i=0;i<4;i++){
      int ch0 = i*256 + wid*64;
      int ch = ch0 + lane;
      int r = ch >> 3, c = ch & 7;
      int cs = c ^ (r & 7);
      gld16(A  + (size_t)(row0+r)*K + k0 + cs*8, (char*)As + ch0*16);
      gld16(Bt + (size_t)(col0+r)*K + k0 + cs*8, (char*)Bs + ch0*16);
    }
    __syncthreads();
    #pragma unroll
    for (int kk=0; kk<2; kk++){
      bf16x8 a[4], b[4];
      #pragma unroll
      for (int i=0;i<4;i++) a[i] = *(const bf16x8*)(As + (wr + i*16 + l)*64 + (((kk*4+g)^l7)*8));
      #pragma unroll
      for (int j=0;j<4;j++) b[j] = *(const bf16x8*)(Bs + (wc + j*16 + l)*64 + (((kk*4+g)^l7)*8));
      #pragma unroll
      for (int i=0;i<4;i++)
        #pragma unroll
        for (int j=0;j<4;j++)
          acc[i][j] = __builtin_amdgcn_mfma_f32_16x16x32_bf16(a[i], b[j], acc[i][j], 0, 0, 0);
    }
  }
  u16* P = Op + (size_t)blockIdx.z*4194304;
  #pragma unroll
  for (int i=0;i<4;i++)
   #pragma unroll
   for (int j=0;j<4;j++)
    #pragma unroll
    for (int r=0;r<4;r++){
      int row = row0 + wr + i*16 + g*4 + r;
      int col = col0 + wc + j*16 + l;
      P[(size_t)row*Nc + col] = f2bf(acc[i][j][r]);
    }
}

// ---------- out = Qint + Pd0..Pd3 (bf16 partials, 4-way split-K) ----------
__global__ __launch_bounds__(256) void reduce_out(const float* __restrict__ Qint,
    const u16* __restrict__ P, float* __restrict__ out){
  size_t i = (size_t)blockIdx.x*256 + threadIdx.x;
  float4 a  = ((const float4*)Qint)[i];
  ushort4 p0 = ((const ushort4*)P)[i];
  ushort4 p1 = ((const ushort4*)(P + 4194304))[i];
  ushort4 p2 = ((const ushort4*)(P + 8388608))[i];
  ushort4 p3 = ((const ushort4*)(P + 12582912))[i];
  float4 o;
  o.x = a.x + (bf2f(p0.x) + bf2f(p1.x)) + (bf2f(p2.x) + bf2f(p3.x));
  o.y = a.y + (bf2f(p0.y) + bf2f(p1.y)) + (bf2f(p2.y) + bf2f(p3.y));
  o.z = a.z + (bf2f(p0.z) + bf2f(p1.z)) + (bf2f(p2.z) + bf2f(p3.z));
  o.w = a.w + (bf2f(p0.w) + bf2f(p1.w)) + (bf2f(p2.w) + bf2f(p3.w));
  ((float4*)out)[i] = o;
}

// ---------- linear attention with relu^2, flash-style ----------
// Q-fragments in registers (loop-invariant). LDS = sK 16 + sV 16 + sW 32 = 64KB -> 2 blocks/CU.
// W-pack uses v_cvt_pk_bf16_f32 (1 op / 2 floats) instead of 4x manual-rounding f2bf.
__global__ __launch_bounds__(256, 2) void attn_kernel(
    const u16* __restrict__ PhiQ, const u16* __restrict__ PhiK,
    const u16* __restrict__ Vt, u16* __restrict__ Mb)
{
  __shared__ u16 sK[2][128][32];
  __shared__ u16 sV[4][64][32];
  __shared__ u16 sW[128*128];
  const int tid = threadIdx.x, wid = tid>>6, lane = tid&63;
  const int g = lane>>4, l = lane&15;
  const int l3 = l & 3;
  const int q0 = blockIdx.x*128, bh = blockIdx.y;
  const u16* Q  = PhiQ + (size_t)bh*2048*64;
  const u16* Kb = PhiK + (size_t)bh*2048*64;
  const u16* V  = Vt   + (size_t)bh*64*2048;
  bf16x8 bq[8][2];
  #pragma unroll
  for (int ct=0;ct<8;ct++)
    #pragma unroll
    for (int ks=0;ks<2;ks++)
      bq[ct][ks] = *(const bf16x8*)(Q + (size_t)(q0 + ct*16 + l)*64 + ks*32 + g*8);
  f32x4 accO[2][4] = {};
  float rsum[8] = {0.f,0.f,0.f,0.f,0.f,0.f,0.f,0.f};
  for (int m0 = 0; m0 < 2048; m0 += 128){
    __syncthreads();
    #pragma unroll
    for (int ks=0; ks<2; ks++)
      #pragma unroll
      for (int i=0;i<2;i++){
        int ch0 = i*256 + wid*64;
        int ch = ch0 + lane;
        int r = ch >> 2, q = ch & 3;
        int qs = q ^ (r & 3);
        gld16(Kb + (size_t)(m0+r)*64 + ks*32 + qs*8, (char*)&sK[ks][0][0] + ch0*16);
      }
    #pragma unroll
    for (int c=0; c<4; c++){
      int ch0 = wid*64;
      int ch = ch0 + lane;
      int d = ch >> 2, q = ch & 3;
      int qs = q ^ (d & 3);
      gld16(V + (size_t)d*2048 + m0 + c*32 + qs*8, (char*)&sV[c][0][0] + ch0*16);
    }
    __syncthreads();
    f32x4 st[2][8] = {};
    bf16x8 ak[2][2];
    #pragma unroll
    for (int rt=0;rt<2;rt++)
      #pragma unroll
      for (int ks=0;ks<2;ks++)
        ak[rt][ks] = *(const bf16x8*)&sK[ks][wid*32 + rt*16 + l][(g^l3)*8];
    #pragma unroll
    for (int ct=0;ct<8;ct++){
      #pragma unroll
      for (int ks=0;ks<2;ks++){
        st[0][ct] = __builtin_amdgcn_mfma_f32_16x16x32_bf16(ak[0][ks], bq[ct][ks], st[0][ct], 0,0,0);
        st[1][ct] = __builtin_amdgcn_mfma_f32_16x16x32_bf16(ak[1][ks], bq[ct][ks], st[1][ct], 0,0,0);
      }
    }
    #pragma unroll
    for (int ct=0;ct<8;ct++){
      float part = 0.f;
      #pragma unroll
      for (int rt=0;rt<2;rt++){
        float s0 = fmaxf(st[rt][ct][0], 0.f), s1 = fmaxf(st[rt][ct][1], 0.f);
        float s2 = fmaxf(st[rt][ct][2], 0.f), s3 = fmaxf(st[rt][ct][3], 0.f);
        float w0 = s0*s0, w1 = s1*s1, w2 = s2*s2, w3 = s3*s3;
        part += (w0 + w1) + (w2 + w3);
        int n = ct*16 + l;
        int mblk = wid*4 + rt*2 + (g>>1);
        *(uint2*)(sW + n*128 + ((mblk ^ l)*8) + (g&1)*4) = pkbf4(w0, w1, w2, w3);
      }
      rsum[ct] += part;
    }
    __syncthreads();
    #pragma unroll
    for (int ks=0;ks<4;ks++){
      int n0 = wid*32 + l, n1 = wid*32 + 16 + l;
      bf16x8 aw0 = *(const bf16x8*)(sW + n0*128 + (((ks*4+g) ^ (n0&15))*8));
      bf16x8 aw1 = *(const bf16x8*)(sW + n1*128 + (((ks*4+g) ^ (n1&15))*8));
      #pragma unroll
      for (int ct=0;ct<4;ct++){
        bf16x8 bv = *(const bf16x8*)&sV[ks][ct*16 + l][(g^l3)*8];
        accO[0][ct] = __builtin_amdgcn_mfma_f32_16x16x32_bf16(aw0, bv, accO[0][ct], 0,0,0);
        accO[1][ct] = __builtin_amdgcn_mfma_f32_16x16x32_bf16(aw1, bv, accO[1][ct], 0,0,0);
      }
    }
  }
  __syncthreads();
  float* sRS = (float*)sW;
  float* sNorm = ((float*)sW) + 512;
  #pragma unroll
  for (int ct=0;ct<8;ct++){
    float v = rsum[ct];
    v += __shfl_xor(v, 16);
    v += __shfl_xor(v, 32);
    rsum[ct] = v;
  }
  if (g == 0){
    #pragma unroll
    for (int ct=0;ct<8;ct++) sRS[wid*128 + ct*16 + l] = rsum[ct];
  }
  __syncthreads();
  if (tid < 128) sNorm[tid] = sRS[tid] + sRS[128+tid] + sRS[256+tid] + sRS[384+tid] + 1.0f;
  __syncthreads();
  const int bb = bh >> 4, h = bh & 15;
  #pragma unroll
  for (int rt=0;rt<2;rt++)
   #pragma unroll
   for (int ct=0;ct<4;ct++)
    #pragma unroll
    for (int r=0;r<4;r++){
      int n = wid*32 + rt*16 + g*4 + r;
      int d = ct*16 + l;
      float norm = sNorm[n];
      float vv = bf2f(V[(size_t)d*2048 + q0 + n]);
      float mv = accO[rt][ct][r]/norm - vv;
      Mb[((size_t)(bb*2048) + q0 + n)*1024 + h*64 + d] = f2bf(mv);
    }
}

// ---------- depthwise conv along n (KS=3, pad=1, per batch) ----------
__global__ __launch_bounds__(256) void conv_kernel(const u16* __restrict__ Hf, const float* __restrict__ w,
                                                   u16* __restrict__ Cv){
  int row = blockIdx.y;
  int n = row & 2047;
  int c0 = (blockIdx.x*256 + threadIdx.x)*8;
  us8v h0 = {0,0,0,0,0,0,0,0}, h2 = {0,0,0,0,0,0,0,0};
  us8v h1 = *(const us8v*)(Hf + (size_t)row*4096 + c0);
  if (n > 0)    h0 = *(const us8v*)(Hf + (size_t)(row-1)*4096 + c0);
  if (n < 2047) h2 = *(const us8v*)(Hf + (size_t)(row+1)*4096 + c0);
  us8v o;
  #pragma unroll
  for (int e=0;e<8;e++){
    int c = c0 + e;
    float acc = bf2f(h0[e])*w[c*3+0] + bf2f(h1[e])*w[c*3+1] + bf2f(h2[e])*w[c*3+2];
    o[e] = f2bf(acc);
  }
  *(us8v*)(Cv + (size_t)row*4096 + c0) = o;
}

extern "C" void kernel_launch(void* const* d_in, const int* in_sizes, int n_in,
                              void* d_out, int out_size, void* d_ws, size_t ws_size,
                              hipStream_t stream)
{
  const float* Q_in  = (const float*)d_in[0];
  const float* X     = (const float*)d_in[1];
  const float* Wq    = (const float*)d_in[2];
  const float* Wk    = (const float*)d_in[3];
  const float* Wv    = (const float*)d_in[4];
  const float* Wo    = (const float*)d_in[5];
  const float* Wup   = (const float*)d_in[6];
  const float* convw = (const float*)d_in[7];
  const float* Wdown = (const float*)d_in[8];
  const float* g1    = (const float*)d_in[9];
  const float* b1    = (const float*)d_in[10];
  const float* g2    = (const float*)d_in[11];
  const float* b2    = (const float*)d_in[12];
  const float* dt    = (const float*)d_in[13];
  float* out = (float*)d_out;

  char* ws = (char*)d_ws;
  const size_t MB = (size_t)1 << 20;
  u16* HcB   = (u16*)(ws + 0*MB);     // 8MB  (dead after QKV gemm)
  u16* WqkvT = (u16*)(ws + 8*MB);     // 6MB  (dead after QKV gemm)
  u16* WoT   = (u16*)(ws + 14*MB);    // 2MB  (dead after Wo gemm)
  u16* PhiQ  = (u16*)(ws + 16*MB);    // 8MB  } contiguous: PhiQ,PhiK,Vt (dead after attn)
  u16* Vt    = (u16*)(ws + 32*MB);    // 8MB
  u16* Mb    = (u16*)(ws + 40*MB);    // 8MB  (dead after Wo gemm)
  u16* Po    = (u16*)(ws + 48*MB);    // 16MB 2x bf16 partials (dead after ln2)
  u16* WupT  = (u16*)(ws + 80*MB);    // 16MB
  u16* WdT   = (u16*)(ws + 96*MB);    // 8MB
  float* Qint = (float*)(ws + 104*MB);// 16MB
  u16* Qn2   = (u16*)(ws + 120*MB);   // 8MB  (dead after Wup gemm)
  u16* Hf    = (u16*)(ws + 0*MB);     // 32MB (written after Wup gemm; old region dead)
  u16* Cv    = (u16*)(ws + 40*MB);    // 32MB (over Mb+Po, both dead by conv)
  u16* Pd    = (u16*)(ws + 0*MB);     // 32MB 4x bf16 partials (over Hf, dead after conv)
  u16* PhiK  = PhiQ + 4194304;

  // transposes (64x64 coalesced tiles) + ln1 fused
  tr_all<<<8192, 256, 0, stream>>>(Wq, Wk, Wv, Wo, Wup, Wdown,
                                   WqkvT, WoT, WupT, WdT,
                                   Q_in, X, g1, b1, HcB);

  // fused QKV projection: [4096][1024] @ [3072][1024]^T
  gemm_qkv<<<dim3(32, 24), 256, 0, stream>>>(HcB, WqkvT, PhiQ);

  attn_kernel<<<dim3(16, 32), 256, 0, stream>>>(PhiQ, PhiK, Vt, Mb);

  // Wo projection, split-K=2 -> bf16 partials
  gemm_part<<<dim3(32, 8, 2), 256, 0, stream>>>(Mb, WoT, 1024, 1024, 512, Po);

  // Qint = Q_in + softplus(dt)*(Po0+Po1); Qn2 = LN(Qint)
  ln2_kernel<<<4096, 256, 0, stream>>>(Po, Q_in, dt, g2, b2, Qint, Qn2);

  // Wup with fused silu(G)*U epilogue -> Hf [4096][4096], wide 256x128 tiles, BK=64
  gemm_wide_up<<<1024, 256, 0, stream>>>(Qn2, WupT, Hf);

  conv_kernel<<<dim3(2, 4096), 256, 0, stream>>>(Hf, convw, Cv);

  // Wdown: wide 256x128 tiles, split-K=4 -> 4x bf16 partials, then out = Qint + sum(Pd)
  gemm_wide_down<<<dim3(16, 8, 4), 256, 0, stream>>>(Cv, WdT, Pd);
  reduce_out<<<4096, 256, 0, stream>>>(Qint, Pd, out);
}